// Round 4
// baseline (134.813 us; speedup 1.0000x reference)
//
#include <hip/hip_runtime.h>
#include <hip/hip_bf16.h>
#include <stdint.h>

#define B_N 4096
#define V_N 2
#define D_N 1024
#define EPS 1e-8f
#define NT2 16              // 4096/256 tiles per dim
#define NTRI2 (NT2*(NT2+1)/2)   // 136 = 8*17 -> clean XCD chunking
#define NKT 32              // K-tiles of BK=32

typedef __attribute__((ext_vector_type(8))) short short8;
typedef __attribute__((ext_vector_type(4))) float f32x4;

__device__ __forceinline__ unsigned int f2mono(float f) {
    unsigned int u = __float_as_uint(f);
    return (u & 0x80000000u) ? ~u : (u | 0x80000000u);
}

__device__ __forceinline__ unsigned short f2bf(float f) {
    __hip_bfloat16 h = __float2bfloat16(f);
    return __builtin_bit_cast(unsigned short, h);
}

__device__ __forceinline__ unsigned long long shfl_xor_u64(unsigned long long v, int m) {
    unsigned int lo = (unsigned int)v, hi = (unsigned int)(v >> 32);
    lo = __shfl_xor(lo, m, 64);
    hi = __shfl_xor(hi, m, 64);
    return ((unsigned long long)hi << 32) | lo;
}

#define GLD16(src, dst) __builtin_amdgcn_global_load_lds(                      \
    (const __attribute__((address_space(1))) unsigned int*)(src),             \
    (__attribute__((address_space(3))) unsigned int*)(dst), 16, 0, 0)

// ---------------- Kernel 1: L2-normalize, emit bf16 (V,B,D) ----------------
__global__ __launch_bounds__(256) void knorm(const float* __restrict__ x,
                                             unsigned short* __restrict__ xbf) {
    int r = blockIdx.x;            // r = b*V + v  (input rows are contiguous)
    int b = r >> 1, v = r & 1;
    const float* row = x + (size_t)r * D_N;
    int t = threadIdx.x;
    float4 val = reinterpret_cast<const float4*>(row)[t];
    float ss = val.x * val.x + val.y * val.y + val.z * val.z + val.w * val.w;
    #pragma unroll
    for (int s = 32; s > 0; s >>= 1) ss += __shfl_xor(ss, s, 64);
    __shared__ float wsum[4];
    if ((t & 63) == 0) wsum[t >> 6] = ss;
    __syncthreads();
    float tot = wsum[0] + wsum[1] + wsum[2] + wsum[3];
    float rn = 1.0f / sqrtf(tot + EPS);
    ushort4 o;
    o.x = f2bf(val.x * rn);
    o.y = f2bf(val.y * rn);
    o.z = f2bf(val.z * rn);
    o.w = f2bf(val.w * rn);
    unsigned short* orow = xbf + ((size_t)v * B_N + b) * D_N;
    reinterpret_cast<ushort4*>(orow)[t] = o;
}

// ------- Kernel 2: per-view X·X^T row-argmax, 256^2 tile, counted-vmcnt ----
// 8 waves (2M x 4N), per-wave 128x64 output, BK=32, 4-deep LDS ring.
// T1 XCD chunking, T2 XOR swizzle, T3+T4 counted vmcnt(8) pipeline, T5 setprio.
#define STAGE(buf, t) do {                                                     \
    const int _o = (t) * 32;                                                   \
    GLD16(pA0 + _o, lsA + (buf) * 8192 + wid * 512);                           \
    GLD16(pA1 + _o, lsA + (buf) * 8192 + 4096 + wid * 512);                    \
    GLD16(pB0 + _o, lsB + (buf) * 8192 + wid * 512);                           \
    GLD16(pB1 + _o, lsB + (buf) * 8192 + 4096 + wid * 512);                    \
} while (0)

#define COMPUTE(buf) do {                                                      \
    const unsigned short* la = lsA + (buf) * 8192;                             \
    const unsigned short* lb = lsB + (buf) * 8192;                             \
    short8 af[8], bfr[4];                                                      \
    _Pragma("unroll")                                                          \
    for (int m = 0; m < 8; m++)                                                \
        af[m] = *reinterpret_cast<const short8*>(                              \
            &la[(wr * 128 + m * 16 + (lane & 15)) * 32 + rslot]);              \
    _Pragma("unroll")                                                          \
    for (int n = 0; n < 4; n++)                                                \
        bfr[n] = *reinterpret_cast<const short8*>(                             \
            &lb[(wc * 64 + n * 16 + (lane & 15)) * 32 + rslot]);               \
    __builtin_amdgcn_s_setprio(1);                                             \
    _Pragma("unroll")                                                          \
    for (int m = 0; m < 8; m++)                                                \
        _Pragma("unroll")                                                      \
        for (int n = 0; n < 4; n++)                                            \
            acc[m][n] = __builtin_amdgcn_mfma_f32_16x16x32_bf16(               \
                af[m], bfr[n], acc[m][n], 0, 0, 0);                            \
    __builtin_amdgcn_s_setprio(0);                                             \
} while (0)

__global__ __launch_bounds__(512, 2) void kargmax(const unsigned short* __restrict__ xbf,
                                                  unsigned long long* __restrict__ rowmax) {
    __shared__ unsigned short lsA[4 * 8192];   // 4 bufs x 256x32 bf16 = 64 KB
    __shared__ unsigned short lsB[4 * 8192];   // 64 KB

    const int v = blockIdx.y;
    // T1: chunked XCD swizzle (bijective: 136 = 8*17)
    const int bxr = (blockIdx.x & 7) * (NTRI2 / 8) + (blockIdx.x >> 3);
    int ti = (int)((sqrtf(8.f * (float)bxr + 1.f) - 1.f) * 0.5f);
    while ((ti + 1) * (ti + 2) / 2 <= bxr) ti++;
    while (ti * (ti + 1) / 2 > bxr) ti--;
    const int tj = bxr - ti * (ti + 1) / 2;
    const int i0 = ti * 256, j0 = tj * 256;
    const bool diag = (ti == tj);
    const unsigned short* Xv = xbf + (size_t)v * B_N * D_N;

    const int tid = threadIdx.x;
    const int wid = tid >> 6, lane = tid & 63;
    const int wr = wid >> 2, wc = wid & 3;       // 2M x 4N waves

    f32x4 acc[8][4];
    #pragma unroll
    for (int m = 0; m < 8; m++)
        #pragma unroll
        for (int n = 0; n < 4; n++) acc[m][n] = (f32x4){0.f, 0.f, 0.f, 0.f};

    // Staging source (per lane). Linear LDS slot (lane&3) holds logical
    // K-chunk (lane&3)^(row&3); row within 16-row chunk = lane>>2.
    const int lrow = lane >> 2;
    const int lswz = ((lane & 3) ^ (lrow & 3)) * 8;
    const unsigned short* pA0 = Xv + (size_t)(i0 + wid * 16 + lrow) * D_N + lswz;
    const unsigned short* pA1 = Xv + (size_t)(i0 + 128 + wid * 16 + lrow) * D_N + lswz;
    const unsigned short* pB0 = Xv + (size_t)(j0 + wid * 16 + lrow) * D_N + lswz;
    const unsigned short* pB1 = Xv + (size_t)(j0 + 128 + wid * 16 + lrow) * D_N + lswz;

    // Read-side swizzled slot: logical chunk (lane>>4) at row with row&3==lane&3.
    const int rslot = ((lane >> 4) ^ (lane & 3)) * 8;

    // ---- Prologue: 3 K-tiles in flight ----
    STAGE(0, 0);
    STAGE(1, 1);
    STAGE(2, 2);
    asm volatile("s_waitcnt vmcnt(8)" ::: "memory");   // tile 0 landed
    __builtin_amdgcn_s_barrier();

    // ---- Main loop: stage t+3, compute t, retire t+1 (vmcnt never 0) ----
    for (int t = 0; t < NKT - 3; ++t) {
        STAGE((t + 3) & 3, t + 3);
        COMPUTE(t & 3);
        asm volatile("s_waitcnt vmcnt(8)" ::: "memory");   // tile t+1 landed
        __builtin_amdgcn_s_barrier();
    }
    COMPUTE((NKT - 3) & 3);
    asm volatile("s_waitcnt vmcnt(4)" ::: "memory");
    __builtin_amdgcn_s_barrier();
    COMPUTE((NKT - 2) & 3);
    asm volatile("s_waitcnt vmcnt(0)" ::: "memory");
    __builtin_amdgcn_s_barrier();
    COMPUTE((NKT - 1) & 3);

    // ---- Epilogue A: row side (rows i0.., cols j0..) ----
    // C/D layout: col = lane&15, row = (lane>>4)*4 + reg  [m89/m91-verified]
    #pragma unroll
    for (int m = 0; m < 8; m++) {
        int rbase = i0 + wr * 128 + m * 16;
        #pragma unroll
        for (int j = 0; j < 4; j++) {
            int grow = rbase + (lane >> 4) * 4 + j;
            unsigned long long best = 0ull;
            #pragma unroll
            for (int n = 0; n < 4; n++) {
                int gcol = j0 + wc * 64 + n * 16 + (lane & 15);
                float vdot = acc[m][n][j];
                unsigned long long p = (grow == gcol)
                    ? 0ull
                    : ((unsigned long long)f2mono(vdot) << 32) | (unsigned int)(~(unsigned int)gcol);
                best = p > best ? p : best;
            }
            #pragma unroll
            for (int s = 1; s < 16; s <<= 1) {
                unsigned long long o = shfl_xor_u64(best, s);
                best = o > best ? o : best;
            }
            if ((lane & 15) == 0)
                atomicMax(&rowmax[(size_t)v * B_N + grow], best);
        }
    }

    // ---- Epilogue B: transposed side (rows j0.., cols i0..), off-diag only ----
    if (!diag) {
        #pragma unroll
        for (int n = 0; n < 4; n++) {
            int growT = j0 + wc * 64 + n * 16 + (lane & 15);
            unsigned long long best = 0ull;
            #pragma unroll
            for (int m = 0; m < 8; m++) {
                int ibase = i0 + wr * 128 + m * 16 + (lane >> 4) * 4;
                #pragma unroll
                for (int j = 0; j < 4; j++) {
                    int gi = ibase + j;
                    float vdot = acc[m][n][j];
                    unsigned long long p =
                        ((unsigned long long)f2mono(vdot) << 32) | (unsigned int)(~(unsigned int)gi);
                    best = p > best ? p : best;
                }
            }
            #pragma unroll
            for (int s = 16; s < 64; s <<= 1) {
                unsigned long long o = shfl_xor_u64(best, s);
                best = o > best ? o : best;
            }
            if (lane < 16)
                atomicMax(&rowmax[(size_t)v * B_N + growT], best);
        }
    }
}

// ------ Kernel 3: exact fp32 distance for selected pairs, per-row loss -----
__global__ __launch_bounds__(256) void kdist(const float* __restrict__ x,
                                             const unsigned long long* __restrict__ rowmax,
                                             float* __restrict__ loss) {
    int idx = blockIdx.x;              // v*B + b
    int v = idx >> 12;
    int b = idx & (B_N - 1);
    unsigned long long p = rowmax[idx];
    int j = (int)(~(unsigned int)(p & 0xffffffffull));
    const float* pa = x + ((size_t)b * V_N + v) * D_N;
    const float* pc = x + ((size_t)j * V_N + v) * D_N;
    int t = threadIdx.x;
    float4 a = reinterpret_cast<const float4*>(pa)[t];
    float4 c = reinterpret_cast<const float4*>(pc)[t];
    float saa = a.x * a.x + a.y * a.y + a.z * a.z + a.w * a.w;
    float scc = c.x * c.x + c.y * c.y + c.z * c.z + c.w * c.w;
    float sac = a.x * c.x + a.y * c.y + a.z * c.z + a.w * c.w;
    #pragma unroll
    for (int s = 32; s > 0; s >>= 1) {
        saa += __shfl_xor(saa, s, 64);
        scc += __shfl_xor(scc, s, 64);
        sac += __shfl_xor(sac, s, 64);
    }
    __shared__ float r0[4], r1[4], r2[4];
    if ((t & 63) == 0) { r0[t >> 6] = saa; r1[t >> 6] = scc; r2[t >> 6] = sac; }
    __syncthreads();
    if (t == 0) {
        saa = r0[0] + r0[1] + r0[2] + r0[3];
        scc = r1[0] + r1[1] + r1[2] + r1[3];
        sac = r2[0] + r2[1] + r2[2] + r2[3];
        float na = sqrtf(saa + EPS), nc = sqrtf(scc + EPS);
        float d2 = saa / (na * na) + scc / (nc * nc) - 2.0f * sac / (na * nc);
        d2 = fmaxf(d2, 0.0f);
        float dist = sqrtf(d2);
        loss[idx] = -logf(dist + EPS);
    }
}

// --------------- Kernel 4: deterministic reduction to scalar ---------------
__global__ __launch_bounds__(256) void kreduce(const float* __restrict__ loss,
                                               float* __restrict__ out) {
    __shared__ float s[256];
    float acc = 0.f;
    for (int i = threadIdx.x; i < V_N * B_N; i += 256) acc += loss[i];
    s[threadIdx.x] = acc;
    __syncthreads();
    #pragma unroll
    for (int step = 128; step > 0; step >>= 1) {
        if (threadIdx.x < step) s[threadIdx.x] += s[threadIdx.x + step];
        __syncthreads();
    }
    if (threadIdx.x == 0) out[0] = s[0] * (1.0f / (float)B_N);
}

extern "C" void kernel_launch(void* const* d_in, const int* in_sizes, int n_in,
                              void* d_out, int out_size, void* d_ws, size_t ws_size,
                              hipStream_t stream) {
    const float* x = (const float*)d_in[0];
    float* out = (float*)d_out;
    char* ws = (char*)d_ws;

    unsigned short* xbf = (unsigned short*)ws;                          // 16 MB
    unsigned long long* rowmax = (unsigned long long*)(ws + 16777216);  // 64 KB
    float* loss = (float*)(ws + 16777216 + 65536);                      // 32 KB

    hipMemsetAsync(rowmax, 0, (size_t)V_N * B_N * sizeof(unsigned long long), stream);
    knorm<<<B_N * V_N, 256, 0, stream>>>(x, xbf);
    kargmax<<<dim3(NTRI2, V_N), 512, 0, stream>>>(xbf, rowmax);
    kdist<<<V_N * B_N, 256, 0, stream>>>(x, rowmax, loss);
    kreduce<<<1, 256, 0, stream>>>(loss, out);
}

// Round 5
// 113.203 us; speedup vs baseline: 1.1909x; 1.1909x over previous
//
#include <hip/hip_runtime.h>
#include <hip/hip_bf16.h>
#include <stdint.h>

#define B_N 4096
#define V_N 2
#define D_N 1024
#define EPS 1e-8f
#define NT2 16                  // 4096/256 tiles per dim
#define NTRI2 (NT2*(NT2+1)/2)   // 136 = 8*17 -> clean XCD chunking
#define NSLAB 32                // K-slabs of 32

typedef __attribute__((ext_vector_type(8))) short short8;
typedef __attribute__((ext_vector_type(4))) float f32x4;

__device__ __forceinline__ unsigned int f2mono(float f) {
    unsigned int u = __float_as_uint(f);
    return (u & 0x80000000u) ? ~u : (u | 0x80000000u);
}

__device__ __forceinline__ unsigned short f2bf(float f) {
    __hip_bfloat16 h = __float2bfloat16(f);
    return __builtin_bit_cast(unsigned short, h);
}

__device__ __forceinline__ unsigned long long shfl_xor_u64(unsigned long long v, int m) {
    unsigned int lo = (unsigned int)v, hi = (unsigned int)(v >> 32);
    lo = __shfl_xor(lo, m, 64);
    hi = __shfl_xor(hi, m, 64);
    return ((unsigned long long)hi << 32) | lo;
}

#define GLD16(src, dst) __builtin_amdgcn_global_load_lds(                      \
    (const __attribute__((address_space(1))) unsigned int*)(src),             \
    (__attribute__((address_space(3))) unsigned int*)(dst), 16, 0, 0)

// ---------------- Kernel 1: L2-normalize, emit bf16 (V,B,D) ----------------
__global__ __launch_bounds__(256) void knorm(const float* __restrict__ x,
                                             unsigned short* __restrict__ xbf) {
    int r = blockIdx.x;            // r = b*V + v  (input rows are contiguous)
    int b = r >> 1, v = r & 1;
    const float* row = x + (size_t)r * D_N;
    int t = threadIdx.x;
    float4 val = reinterpret_cast<const float4*>(row)[t];
    float ss = val.x * val.x + val.y * val.y + val.z * val.z + val.w * val.w;
    #pragma unroll
    for (int s = 32; s > 0; s >>= 1) ss += __shfl_xor(ss, s, 64);
    __shared__ float wsum[4];
    if ((t & 63) == 0) wsum[t >> 6] = ss;
    __syncthreads();
    float tot = wsum[0] + wsum[1] + wsum[2] + wsum[3];
    float rn = 1.0f / sqrtf(tot + EPS);
    ushort4 o;
    o.x = f2bf(val.x * rn);
    o.y = f2bf(val.y * rn);
    o.z = f2bf(val.z * rn);
    o.w = f2bf(val.w * rn);
    unsigned short* orow = xbf + ((size_t)v * B_N + b) * D_N;
    reinterpret_cast<ushort4*>(orow)[t] = o;
}

// ------- Kernel 2: per-view X·X^T row-argmax, 256^2 tile, 2-phase slabs ----
// 8 waves (2M x 4N), wave tile 128x64, BK=32 slabs, 4-deep LDS ring (128 KB).
// Per slab: 2 phases of {ds_read + stage-issue; barrier; setprio+16 MFMA; barrier},
// vmcnt(8) once per slab (T3+T4 counted, never 0 in main loop).
// Swizzle: LDS[row][slot] holds K-chunk slot^((row>>1)&3)  (bank-conflict-free).

#define STAGE_A(r, t) do {                                                     \
    const unsigned short* _s = pAsrc + (size_t)(t) * 32;                       \
    GLD16(_s,             lsb + (r) * 16384 + wid * 1024);                     \
    GLD16(_s + 16 * D_N,  lsb + (r) * 16384 + wid * 1024 + 512);               \
} while (0)

#define STAGE_B(r, t) do {                                                     \
    const unsigned short* _s = pBsrc + (size_t)(t) * 32;                       \
    GLD16(_s,             lsb + (r) * 16384 + 8192 + wid * 1024);              \
    GLD16(_s + 16 * D_N,  lsb + (r) * 16384 + 8192 + wid * 1024 + 512);        \
} while (0)

// Phase 0 of slab: read all B-frags + A-frags m0..3, stage A of slab t+3.
#define PH0(r, dostage, sr, st) do {                                           \
    const unsigned short* la = lsb + (r) * 16384;                              \
    const unsigned short* lb = la + 8192;                                      \
    _Pragma("unroll")                                                          \
    for (int n = 0; n < 4; n++)                                                \
        bfr[n] = *reinterpret_cast<const short8*>(                             \
            &lb[(wc * 64 + n * 16 + (lane & 15)) * 32 + rslot]);               \
    _Pragma("unroll")                                                          \
    for (int m = 0; m < 4; m++)                                                \
        af[m] = *reinterpret_cast<const short8*>(                              \
            &la[(wr * 128 + m * 16 + (lane & 15)) * 32 + rslot]);              \
    if (dostage) STAGE_A(sr, st);                                              \
    __builtin_amdgcn_s_barrier();                                              \
    __builtin_amdgcn_s_setprio(1);                                             \
    _Pragma("unroll")                                                          \
    for (int m = 0; m < 4; m++)                                                \
        _Pragma("unroll")                                                      \
        for (int n = 0; n < 4; n++)                                            \
            acc[m][n] = __builtin_amdgcn_mfma_f32_16x16x32_bf16(               \
                af[m], bfr[n], acc[m][n], 0, 0, 0);                            \
    __builtin_amdgcn_s_setprio(0);                                             \
    __builtin_amdgcn_s_barrier();                                              \
} while (0)

// Phase 1 of slab: read A-frags m4..7 (reuse bfr), stage B of slab t+3,
// MFMA, then caller-supplied vmcnt + final barrier.
#define PH1(r, dostage, sr, st, VMC) do {                                      \
    const unsigned short* la = lsb + (r) * 16384;                              \
    _Pragma("unroll")                                                          \
    for (int m = 0; m < 4; m++)                                                \
        af[m] = *reinterpret_cast<const short8*>(                              \
            &la[(wr * 128 + (m + 4) * 16 + (lane & 15)) * 32 + rslot]);        \
    if (dostage) STAGE_B(sr, st);                                              \
    __builtin_amdgcn_s_barrier();                                              \
    __builtin_amdgcn_s_setprio(1);                                             \
    _Pragma("unroll")                                                          \
    for (int m = 0; m < 4; m++)                                                \
        _Pragma("unroll")                                                      \
        for (int n = 0; n < 4; n++)                                            \
            acc[m + 4][n] = __builtin_amdgcn_mfma_f32_16x16x32_bf16(           \
                af[m], bfr[n], acc[m + 4][n], 0, 0, 0);                        \
    __builtin_amdgcn_s_setprio(0);                                             \
    asm volatile("s_waitcnt vmcnt(" #VMC ")" ::: "memory");                    \
    __builtin_amdgcn_s_barrier();                                              \
} while (0)

#define SLAB(r, dostage, sr, st, VMC) do {                                     \
    PH0(r, dostage, sr, st);                                                   \
    PH1(r, dostage, sr, st, VMC);                                              \
} while (0)

__global__ __launch_bounds__(512, 1) void kargmax(const unsigned short* __restrict__ xbf,
                                                  unsigned long long* __restrict__ rowmax) {
    __shared__ unsigned short lsb[4 * 16384];   // 4 slabs x (A 256x32 + B 256x32) = 128 KB

    const int v = blockIdx.y;
    // T1: chunked XCD swizzle (bijective: 136 = 8*17)
    const int bxr = (blockIdx.x & 7) * (NTRI2 / 8) + (blockIdx.x >> 3);
    int ti = (int)((sqrtf(8.f * (float)bxr + 1.f) - 1.f) * 0.5f);
    while ((ti + 1) * (ti + 2) / 2 <= bxr) ti++;
    while (ti * (ti + 1) / 2 > bxr) ti--;
    const int tj = bxr - ti * (ti + 1) / 2;
    const int i0 = ti * 256, j0 = tj * 256;
    const bool diag = (ti == tj);
    const unsigned short* Xv = xbf + (size_t)v * B_N * D_N;

    const int tid = threadIdx.x;
    const int wid = tid >> 6, lane = tid & 63;
    const int wr = wid >> 2, wc = wid & 3;       // 2M x 4N waves

    f32x4 acc[8][4];
    #pragma unroll
    for (int m = 0; m < 8; m++)
        #pragma unroll
        for (int n = 0; n < 4; n++) acc[m][n] = (f32x4){0.f, 0.f, 0.f, 0.f};

    // Write side: lane l covers row (l>>2) of a 16-row chunk, linear slot l&3.
    // Source K-chunk = (l&3) ^ ((row>>1)&3) = (l&3) ^ ((l>>3)&3).
    const int csw = ((lane & 3) ^ ((lane >> 3) & 3)) * 8;
    const unsigned short* pAsrc = Xv + (size_t)(i0 + wid * 32 + (lane >> 2)) * D_N + csw;
    const unsigned short* pBsrc = Xv + (size_t)(j0 + wid * 32 + (lane >> 2)) * D_N + csw;

    // Read side: chunk lane>>4 at row rowbase+(lane&15):
    // slot = (lane>>4) ^ ((row>>1)&3); rowbase is a multiple of 16.
    const int rslot = (((lane >> 4) ^ ((lane & 15) >> 1)) & 3) * 8;

    short8 af[4], bfr[4];

    // ---- Prologue: slabs 0,1,2 in flight (12 loads/wave) ----
    STAGE_A(0, 0); STAGE_B(0, 0);
    STAGE_A(1, 1); STAGE_B(1, 1);
    STAGE_A(2, 2); STAGE_B(2, 2);
    asm volatile("s_waitcnt vmcnt(8)" ::: "memory");   // slab 0 landed
    __builtin_amdgcn_s_barrier();

    // ---- Main: slabs 0..27 (ring const via 4x unroll), stage s+3, vmcnt(8) ----
    for (int s = 0; s < 28; s += 4) {
        SLAB(0, true, 3, s + 3, 8);
        SLAB(1, true, 0, s + 4, 8);
        SLAB(2, true, 1, s + 5, 8);
        SLAB(3, true, 2, s + 6, 8);
    }
    // ---- Tail: slab 28 stages 31; 29/30/31 drain ----
    SLAB(0, true, 3, 31, 8);     // s=28: after, slab 29 landed
    SLAB(1, false, 0, 0, 4);     // s=29: slab 30 landed
    SLAB(2, false, 0, 0, 0);     // s=30: slab 31 landed
    SLAB(3, false, 0, 0, 0);     // s=31 (vmcnt(0) no-op: nothing outstanding)

    // ---- Epilogue A: row side (rows i0.., cols j0..) ----
    // C/D layout: col = lane&15, row = (lane>>4)*4 + reg  [m89/m91-verified]
    #pragma unroll
    for (int m = 0; m < 8; m++) {
        int rbase = i0 + wr * 128 + m * 16;
        #pragma unroll
        for (int j = 0; j < 4; j++) {
            int grow = rbase + (lane >> 4) * 4 + j;
            unsigned long long best = 0ull;
            #pragma unroll
            for (int n = 0; n < 4; n++) {
                int gcol = j0 + wc * 64 + n * 16 + (lane & 15);
                float vdot = acc[m][n][j];
                unsigned long long p = (grow == gcol)
                    ? 0ull
                    : ((unsigned long long)f2mono(vdot) << 32) | (unsigned int)(~(unsigned int)gcol);
                best = p > best ? p : best;
            }
            #pragma unroll
            for (int s = 1; s < 16; s <<= 1) {
                unsigned long long o = shfl_xor_u64(best, s);
                best = o > best ? o : best;
            }
            if ((lane & 15) == 0)
                atomicMax(&rowmax[(size_t)v * B_N + grow], best);
        }
    }

    // ---- Epilogue B: transposed side (rows j0.., cols i0..), off-diag only ----
    if (!diag) {
        #pragma unroll
        for (int n = 0; n < 4; n++) {
            int growT = j0 + wc * 64 + n * 16 + (lane & 15);
            unsigned long long best = 0ull;
            #pragma unroll
            for (int m = 0; m < 8; m++) {
                int ibase = i0 + wr * 128 + m * 16 + (lane >> 4) * 4;
                #pragma unroll
                for (int j = 0; j < 4; j++) {
                    int gi = ibase + j;
                    float vdot = acc[m][n][j];
                    unsigned long long p =
                        ((unsigned long long)f2mono(vdot) << 32) | (unsigned int)(~(unsigned int)gi);
                    best = p > best ? p : best;
                }
            }
            #pragma unroll
            for (int s = 16; s < 64; s <<= 1) {
                unsigned long long o = shfl_xor_u64(best, s);
                best = o > best ? o : best;
            }
            if (lane < 16)
                atomicMax(&rowmax[(size_t)v * B_N + growT], best);
        }
    }
}

// ------ Kernel 3: exact fp32 distance for selected pairs, per-row loss -----
__global__ __launch_bounds__(256) void kdist(const float* __restrict__ x,
                                             const unsigned long long* __restrict__ rowmax,
                                             float* __restrict__ loss) {
    int idx = blockIdx.x;              // v*B + b
    int v = idx >> 12;
    int b = idx & (B_N - 1);
    unsigned long long p = rowmax[idx];
    int j = (int)(~(unsigned int)(p & 0xffffffffull));
    const float* pa = x + ((size_t)b * V_N + v) * D_N;
    const float* pc = x + ((size_t)j * V_N + v) * D_N;
    int t = threadIdx.x;
    float4 a = reinterpret_cast<const float4*>(pa)[t];
    float4 c = reinterpret_cast<const float4*>(pc)[t];
    float saa = a.x * a.x + a.y * a.y + a.z * a.z + a.w * a.w;
    float scc = c.x * c.x + c.y * c.y + c.z * c.z + c.w * c.w;
    float sac = a.x * c.x + a.y * c.y + a.z * c.z + a.w * c.w;
    #pragma unroll
    for (int s = 32; s > 0; s >>= 1) {
        saa += __shfl_xor(saa, s, 64);
        scc += __shfl_xor(scc, s, 64);
        sac += __shfl_xor(sac, s, 64);
    }
    __shared__ float r0[4], r1[4], r2[4];
    if ((t & 63) == 0) { r0[t >> 6] = saa; r1[t >> 6] = scc; r2[t >> 6] = sac; }
    __syncthreads();
    if (t == 0) {
        saa = r0[0] + r0[1] + r0[2] + r0[3];
        scc = r1[0] + r1[1] + r1[2] + r1[3];
        sac = r2[0] + r2[1] + r2[2] + r2[3];
        float na = sqrtf(saa + EPS), nc = sqrtf(scc + EPS);
        float d2 = saa / (na * na) + scc / (nc * nc) - 2.0f * sac / (na * nc);
        d2 = fmaxf(d2, 0.0f);
        float dist = sqrtf(d2);
        loss[idx] = -logf(dist + EPS);
    }
}

// --------------- Kernel 4: deterministic reduction to scalar ---------------
__global__ __launch_bounds__(256) void kreduce(const float* __restrict__ loss,
                                               float* __restrict__ out) {
    __shared__ float s[256];
    float acc = 0.f;
    for (int i = threadIdx.x; i < V_N * B_N; i += 256) acc += loss[i];
    s[threadIdx.x] = acc;
    __syncthreads();
    #pragma unroll
    for (int step = 128; step > 0; step >>= 1) {
        if (threadIdx.x < step) s[threadIdx.x] += s[threadIdx.x + step];
        __syncthreads();
    }
    if (threadIdx.x == 0) out[0] = s[0] * (1.0f / (float)B_N);
}

extern "C" void kernel_launch(void* const* d_in, const int* in_sizes, int n_in,
                              void* d_out, int out_size, void* d_ws, size_t ws_size,
                              hipStream_t stream) {
    const float* x = (const float*)d_in[0];
    float* out = (float*)d_out;
    char* ws = (char*)d_ws;

    unsigned short* xbf = (unsigned short*)ws;                          // 16 MB
    unsigned long long* rowmax = (unsigned long long*)(ws + 16777216);  // 64 KB
    float* loss = (float*)(ws + 16777216 + 65536);                      // 32 KB

    hipMemsetAsync(rowmax, 0, (size_t)V_N * B_N * sizeof(unsigned long long), stream);
    knorm<<<B_N * V_N, 256, 0, stream>>>(x, xbf);
    kargmax<<<dim3(NTRI2, V_N), 512, 0, stream>>>(xbf, rowmax);
    kdist<<<V_N * B_N, 256, 0, stream>>>(x, rowmax, loss);
    kreduce<<<1, 256, 0, stream>>>(loss, out);
}